// Round 12
// baseline (1006.745 us; speedup 1.0000x reference)
//
#include <hip/hip_runtime.h>

#define MAX_ITER 8192
#define NCHUNK   64
#define NCHUNKS  128          // MAX_ITER / NCHUNK
#define NSCAN    64           // scanner blocks, 1 sample each
#define NTHREADS 256
#define MAGIC    0x13572468u

typedef unsigned long long u64;
#define KEY_MAX 0xffffffffffffffffull

// IEEE fp32 ops, contraction off -> bitwise numpy match (verified rounds 2-8).
__device__ __forceinline__ float mul_rn(float a, float b) {
#pragma clang fp contract(off)
  return a * b;
}
__device__ __forceinline__ float add_rn(float a, float b) {
#pragma clang fp contract(off)
  return a + b;
}
__device__ __forceinline__ float sub_rn(float a, float b) {
#pragma clang fp contract(off)
  return a - b;
}
__device__ __forceinline__ float bcastf(float v, int lane) {
  return __int_as_float(__builtin_amdgcn_readlane(__float_as_int(v), lane));
}
__device__ __forceinline__ void st_agent(u64* p, u64 v) {
  __hip_atomic_store(p, v, __ATOMIC_RELAXED, __HIP_MEMORY_SCOPE_AGENT);
}
__device__ __forceinline__ u64 ld_agent(u64* p) {
  return __hip_atomic_load(p, __ATOMIC_RELAXED, __HIP_MEMORY_SCOPE_AGENT);
}
__device__ __forceinline__ void st_agent32(unsigned* p, unsigned v) {
  __hip_atomic_store(p, v, __ATOMIC_RELAXED, __HIP_MEMORY_SCOPE_AGENT);
}
__device__ __forceinline__ unsigned ld_agent32(unsigned* p) {
  return __hip_atomic_load(p, __ATOMIC_RELAXED, __HIP_MEMORY_SCOPE_AGENT);
}
__device__ __forceinline__ u64 packf2(float x, float y) {
  return ((u64)__float_as_uint(y) << 32) | (u64)__float_as_uint(x);
}
__device__ __forceinline__ void waitcnt_vm0() {
  asm volatile("s_waitcnt vmcnt(0)" ::: "memory");
}
__device__ __forceinline__ void compiler_fence() {
  asm volatile("" ::: "memory");
}
// Exact (d2, idx) lexicographic key (scanners only): d2 >= 0 -> bit-monotonic.
__device__ __forceinline__ u64 mkkey(float d2, int idx) {
  return ((u64)__float_as_uint(d2) << 32) | (u64)(unsigned)idx;
}

__global__ __launch_bounds__(NTHREADS) void rrt_kernel(
    const float* __restrict__ state, const float* __restrict__ goal,
    const float* __restrict__ u, const float* __restrict__ r,
    float* __restrict__ out, unsigned* __restrict__ ws) {
  // scanners hold nodes 1..8064 (max ever scanned); 64512 B < 64 KiB
  __shared__ __align__(16) float2 nodesL[8064];
  __shared__ u64 sharedK[4];

  u64* outU = (u64*)out;                // node i at outU[i] (float2-packed)
  unsigned* nflag = ws;                 // coordinator epoch       (byte 0)
  unsigned* ini   = ws + 32;            // init guard              (byte 128)
  u64* MbufK = (u64*)(ws + 64);         // 64 tagged keys          (byte 256)
  u64* MbufC = (u64*)(ws + 256);        // 64 packed coords        (byte 1024)

  const int tid  = threadIdx.x;
  const int wave = tid >> 6;
  const int lane = tid & 63;
  const int blk  = blockIdx.x;

  const float n0x = state[0], n0y = state[1];
  const float gx = goal[0],  gy = goal[1];

  if (blk == 0) {
    // ================= coordinator: one wave, no LDS, no barriers ==========
    if (tid == 0) {   // d_ws re-poisoned 0xAA each launch: poison tag = 85 != any first-read epoch
      st_agent32(nflag, 0u);
      st_agent(&outU[0], packf2(n0x, n0y));   // node 0
      waitcnt_vm0();
      st_agent32(ini, MAGIC);
    }
    if (tid >= 64) return;

    // current-chunk sample (chunk 0)
    float sx, sy;
    {
      const float uu = u[lane];
      if (uu < 0.1f) { sx = gx; sy = gy; }
      else { sx = mul_rn(r[2 * lane], 200.0f); sy = mul_rn(r[2 * lane + 1], 200.0f); }
    }
    float cbd2 = 3.0e38f, cbx = 0.0f, cby = 0.0f;   // carry over (c-64, c]

    for (int k = 0; k < NCHUNKS; ++k) {
      const int c = k * NCHUNK;
      const bool hasNext = (k < NCHUNKS - 1);

      // prefetch next-chunk sample before the poll (independent L2 loads)
      float nsx = 0.0f, nsy = 0.0f;
      if (hasNext) {
        const int i2 = c + NCHUNK + lane;
        const float uu = u[i2];
        if (uu < 0.1f) { nsx = gx; nsy = gy; }
        else { nsx = mul_rn(r[2 * i2], 200.0f); nsy = mul_rn(r[2 * i2 + 1], 200.0f); }
      }

      // ---- assemble argmin over [0..c]: scanner M [0..c-64] + carry (c-64,c]
      float bd2, bx, by;
      if (k == 0) {
        const float dx = sub_rn(n0x, sx), dy = sub_rn(n0y, sy);
        bd2 = add_rn(mul_rn(dx, dx), mul_rn(dy, dy));
        bx = n0x; by = n0y;
      } else {
        u64 kv;
        for (;;) {   // tag-in-key poll: one coalesced load, all 64 must match k
          kv = ld_agent(&MbufK[lane]);
          if (__all((int)(((unsigned)kv >> 13) & 0x7Fu) == k)) break;
          __builtin_amdgcn_s_sleep(1);
        }
        compiler_fence();
        const u64 cv = ld_agent(&MbufC[lane]);   // valid: C written before K
        const float md2 = __uint_as_float((unsigned)(kv >> 32));
        bd2 = cbd2; bx = cbx; by = cby;
        if (!(bd2 < md2)) {   // M's indices are all lower: M wins ties
          bd2 = md2;
          bx = __uint_as_float((unsigned)(cv & 0xffffffffu));
          by = __uint_as_float((unsigned)(cv >> 32));
        }
      }

      // pre-steer (round-3-verified math)
      float dirx = sub_rn(sx, bx), diry = sub_rn(sy, by);
      float dist = __fsqrt_rn(add_rn(bd2, 1e-12f));
      float scl = (dist > 5.0f) ? __fdiv_rn(5.0f, dist) : 1.0f;
      float nx = add_rn(bx, mul_rn(dirx, scl));
      float ny = add_rn(by, mul_rn(diry, scl));

      float nbd2 = 3.0e38f, nbx = 0.0f, nby = 0.0f;   // next carry

      // ---- 64 sequential steps; float-only (increasing idx => strict < ok)
      #pragma unroll 8
      for (int t = 0; t < NCHUNK; ++t) {
        const float px = bcastf(nx, t);   // node c+t+1
        const float py = bcastf(ny, t);
        if (lane > t) {
          const float dx = sub_rn(px, sx), dy = sub_rn(py, sy);
          const float nd2 = add_rn(mul_rn(dx, dx), mul_rn(dy, dy));
          if (nd2 < bd2) {               // rare: recompute steer
            bd2 = nd2; bx = px; by = py;
            dirx = sub_rn(sx, bx); diry = sub_rn(sy, by);
            dist = __fsqrt_rn(add_rn(nd2, 1e-12f));
            scl = (dist > 5.0f) ? __fdiv_rn(5.0f, dist) : 1.0f;
            nx = add_rn(bx, mul_rn(dirx, scl));
            ny = add_rn(by, mul_rn(diry, scl));
          }
        }
        {  // carried next-chunk update (independent; hides in readlane stalls)
          const float dx = sub_rn(px, nsx), dy = sub_rn(py, nsy);
          const float nd2 = add_rn(mul_rn(dx, dx), mul_rn(dy, dy));
          if (nd2 < nbd2) { nbd2 = nd2; nbx = px; nby = py; }
        }
      }

      st_agent(&outU[c + lane + 1], packf2(nx, ny));
      waitcnt_vm0();                     // wave-level drain of all 64 stores
      if (lane == 0 && hasNext) st_agent32(nflag, (unsigned)(k + 1));

      cbd2 = nbd2; cbx = nbx; cby = nby;
      sx = nsx; sy = nsy;
    }
  } else {
    // ================= scanners: blocks 1..64, one sample each =============
    const int b = blk - 1;
    if (tid == 0) {
      while (ld_agent32(ini) != MAGIC) __builtin_amdgcn_s_sleep(2);
      compiler_fence();
    }
    __syncthreads();

    for (int k = 0; k < NCHUNKS - 1; ++k) {   // iter k -> M_{k+1} over [0..64k]
      const int c = k * NCHUNK;

      if (k >= 1 && wave == 0) {   // poll epoch k; pull newest 64 nodes
        while (ld_agent32(nflag) < (unsigned)k) __builtin_amdgcn_s_sleep(1);
        compiler_fence();
        const int j = c - NCHUNK + 1 + lane;   // nodes (c-64, c]
        const u64 nv = ld_agent(&outU[j]);
        float2 p;
        p.x = __uint_as_float((unsigned)(nv & 0xffffffffu));
        p.y = __uint_as_float((unsigned)(nv >> 32));
        nodesL[j - 1] = p;
      }
      __syncthreads();

      // my sample: chunk k+1, slot b
      float sx, sy;
      {
        const int i = (k + 1) * NCHUNK + b;
        const float uu = u[i];
        if (uu < 0.1f) { sx = gx; sy = gy; }
        else { sx = mul_rn(r[2 * i], 200.0f); sy = mul_rn(r[2 * i + 1], 200.0f); }
      }

      u64 key = KEY_MAX;
      if (tid == 0) {   // node 0
        const float dx = sub_rn(n0x, sx), dy = sub_rn(n0y, sy);
        key = mkkey(add_rn(mul_rn(dx, dx), mul_rn(dy, dy)), 0);
      }
      // 256 lanes stride node pairs; float4 = nodes (j, j+1), j odd
      for (int j = 1 + 2 * tid; j < c; j += 2 * NTHREADS) {
        const float4 p = *(const float4*)&nodesL[j - 1];
        const float dxa = sub_rn(p.x, sx), dya = sub_rn(p.y, sy);
        const u64 ka = mkkey(add_rn(mul_rn(dxa, dxa), mul_rn(dya, dya)), j);
        const float dxb = sub_rn(p.z, sx), dyb = sub_rn(p.w, sy);
        const u64 kb = mkkey(add_rn(mul_rn(dxb, dxb), mul_rn(dyb, dyb)), j + 1);
        if (ka < key) key = ka;     // lower idx first: exact argmin ties
        if (kb < key) key = kb;
      }
      #pragma unroll
      for (int m = 32; m >= 1; m >>= 1) {
        const u64 ok = __shfl_xor(key, m, 64);
        if (ok < key) key = ok;
      }
      if (lane == 0) sharedK[wave] = key;
      __syncthreads();

      if (wave == 0) {
        u64 kk = (lane < 4) ? sharedK[lane] : KEY_MAX;
        u64 ok = __shfl_xor(kk, 1, 64); if (ok < kk) kk = ok;
        ok = __shfl_xor(kk, 2, 64);     if (ok < kk) kk = ok;
        if (lane == 0) {
          const unsigned midx = (unsigned)(kk & 0x1FFFu);   // idx < 8192
          float mx, my;
          if (midx == 0) { mx = n0x; my = n0y; }
          else { const float2 p = nodesL[midx - 1]; mx = p.x; my = p.y; }
          st_agent(&MbufC[b], packf2(mx, my));
          waitcnt_vm0();                                    // C lands before K
          st_agent(&MbufK[b], kk | ((u64)(unsigned)(k + 1) << 13));  // tag
        }
      }
      // next iter's LDS writes (nodes (c, c+64]) are disjoint from this iter's
      // reads and gated by the top-of-loop __syncthreads.
    }
  }
}

extern "C" void kernel_launch(void* const* d_in, const int* in_sizes, int n_in,
                              void* d_out, int out_size, void* d_ws, size_t ws_size,
                              hipStream_t stream) {
  const float* state = (const float*)d_in[0];
  const float* goal  = (const float*)d_in[1];
  const float* u     = (const float*)d_in[2];
  const float* r     = (const float*)d_in[3];
  float* out = (float*)d_out;
  unsigned* ws = (unsigned*)d_ws;
  (void)in_sizes; (void)n_in; (void)out_size; (void)ws_size;
  rrt_kernel<<<NSCAN + 1, NTHREADS, 0, stream>>>(state, goal, u, r, out, ws);
}